// Round 12
// baseline (53.655 us; speedup 1.0000x reference)
//
#include <hip/hip_runtime.h>

#define C_DIM 19
#define G_DIM 8
#define H_DIM 512
#define W_DIM 512
#define B_DIM 4
#define PLANE (H_DIM * W_DIM)
#define NPIX  (B_DIM * PLANE)
#define NT    256

__device__ __forceinline__ unsigned bf16rne(float f) {
    unsigned x = __float_as_uint(f);
    return (x + 0x7fffu + ((x >> 16) & 1u)) >> 16;
}
__device__ __forceinline__ float up_lo(unsigned u) { return __uint_as_float(u << 16); }
__device__ __forceinline__ float up_hi(unsigned u) { return __uint_as_float(u & 0xffff0000u); }

__device__ __forceinline__ void ntstore2(float* p, float f0, float f1) {
    unsigned long long v = (unsigned long long)__float_as_uint(f0) |
                           ((unsigned long long)__float_as_uint(f1) << 32);
    __builtin_nontemporal_store(v, (unsigned long long*)p);
}

// async global -> LDS, 16 B per lane, no VGPR destination.
// LDS dest is wave-uniform base + lane*16 (hardware behavior); global src per-lane.
__device__ __forceinline__ void gload_lds16(const void* g, void* l) {
    __builtin_amdgcn_global_load_lds(
        (const __attribute__((address_space(1))) unsigned int*)g,
        (__attribute__((address_space(3))) unsigned int*)l,
        16, 0, 0);
}

// E = softmax(100*matrix over g): E4[c][0]=g0..3, E4[c][1]=g4..7.  NO sync inside.
__device__ __forceinline__ void build_E_nosync(const float* __restrict__ matrix,
                                               float4 (*E4)[2], int tid) {
    if (tid < C_DIM) {
        const int c = tid;
        float m[G_DIM];
        float mx = -1e30f;
        #pragma unroll
        for (int g = 0; g < G_DIM; ++g) {
            m[g] = 100.0f * matrix[g * C_DIM + c];
            mx = fmaxf(mx, m[g]);
        }
        float s = 0.0f;
        #pragma unroll
        for (int g = 0; g < G_DIM; ++g) { m[g] = __expf(m[g] - mx); s += m[g]; }
        const float inv = 1.0f / s;
        E4[c][0] = make_float4(m[0]*inv, m[1]*inv, m[2]*inv, m[3]*inv);
        E4[c][1] = make_float4(m[4]*inv, m[5]*inv, m[6]*inv, m[7]*inv);
    }
}

// ---- K1: softmax over C + encode to G, 2 px/thread; Qg packed [b][h][w][g] bf16 ----
__global__ __launch_bounds__(NT, 4)
void qg_encode(const float* __restrict__ logit,
               const float* __restrict__ matrix,
               uint4* __restrict__ Qg)
{
    __shared__ float4 E4[C_DIM][2];
    build_E_nosync(matrix, E4, threadIdx.x);
    __syncthreads();

    const int bid = blockIdx.x;
    const int swz = (bid & 7) * (NPIX / (2 * NT) / 8) + (bid >> 3);
    const int t   = swz * NT + threadIdx.x;
    const int px0 = t * 2;
    const int b   = px0 >> 18;
    const int pix = px0 & (PLANE - 1);
    const float* __restrict__ p = logit + (size_t)b * C_DIM * PLANE + pix;

    float eg[G_DIM][2];
    #pragma unroll
    for (int g = 0; g < G_DIM; ++g) { eg[g][0] = 0.0f; eg[g][1] = 0.0f; }
    float s0 = 0.0f, s1 = 0.0f;

    #pragma unroll
    for (int c = 0; c < C_DIM; ++c) {
        const float2 lv = *(const float2*)(p + (size_t)c * PLANE);
        const float e0 = __expf(lv.x);
        const float e1 = __expf(lv.y);
        s0 += e0; s1 += e1;
        const float4 E0 = E4[c][0];
        const float4 E1 = E4[c][1];
        eg[0][0] = fmaf(E0.x, e0, eg[0][0]);  eg[0][1] = fmaf(E0.x, e1, eg[0][1]);
        eg[1][0] = fmaf(E0.y, e0, eg[1][0]);  eg[1][1] = fmaf(E0.y, e1, eg[1][1]);
        eg[2][0] = fmaf(E0.z, e0, eg[2][0]);  eg[2][1] = fmaf(E0.z, e1, eg[2][1]);
        eg[3][0] = fmaf(E0.w, e0, eg[3][0]);  eg[3][1] = fmaf(E0.w, e1, eg[3][1]);
        eg[4][0] = fmaf(E1.x, e0, eg[4][0]);  eg[4][1] = fmaf(E1.x, e1, eg[4][1]);
        eg[5][0] = fmaf(E1.y, e0, eg[5][0]);  eg[5][1] = fmaf(E1.y, e1, eg[5][1]);
        eg[6][0] = fmaf(E1.z, e0, eg[6][0]);  eg[6][1] = fmaf(E1.z, e1, eg[6][1]);
        eg[7][0] = fmaf(E1.w, e0, eg[7][0]);  eg[7][1] = fmaf(E1.w, e1, eg[7][1]);
    }
    {
        const float inv = 1.0f / s0;
        uint4 u;
        u.x = bf16rne(eg[0][0]*inv) | (bf16rne(eg[1][0]*inv) << 16);
        u.y = bf16rne(eg[2][0]*inv) | (bf16rne(eg[3][0]*inv) << 16);
        u.z = bf16rne(eg[4][0]*inv) | (bf16rne(eg[5][0]*inv) << 16);
        u.w = bf16rne(eg[6][0]*inv) | (bf16rne(eg[7][0]*inv) << 16);
        Qg[px0] = u;
    }
    {
        const float inv = 1.0f / s1;
        uint4 u;
        u.x = bf16rne(eg[0][1]*inv) | (bf16rne(eg[1][1]*inv) << 16);
        u.y = bf16rne(eg[2][1]*inv) | (bf16rne(eg[3][1]*inv) << 16);
        u.z = bf16rne(eg[4][1]*inv) | (bf16rne(eg[5][1]*inv) << 16);
        u.w = bf16rne(eg[6][1]*inv) | (bf16rne(eg[7][1]*inv) << 16);
        Qg[px0 + 1] = u;
    }
}

// ---- K2: one block per image row; F + Qg staged via global_load_lds ----
// 2048 blocks x 256 threads, 2 px/thread (512 px = one row).
__global__ __launch_bounds__(NT)
void crf_decode(const float* __restrict__ F,
                const float* __restrict__ logit,
                const float* __restrict__ matrix,
                const uint4* __restrict__ Qg,
                float* __restrict__ out)
{
    __shared__ float4 E4[C_DIM][2];
    __shared__ float  ldsF[9 * W_DIM];   // 18432 B  [k][512]
    __shared__ uint4  ldsQ[3 * W_DIM];   // 24576 B  [r][512]

    const int tid = threadIdx.x;

    // XCD-chunked bijective swizzle; same row<->XCD map as K1's writer
    const int bid = blockIdx.x;
    const int swz = (bid & 7) * 256 + (bid >> 3);   // flat row id: b*512 + y
    const int b   = swz >> 9;
    const int y   = swz & 511;

    // ---- stage F row (HBM-cold stream) FIRST: 9 planes x 2 KB, 1152 uint4 units
    const float* __restrict__ Fb = F + (size_t)b * 9 * PLANE + (size_t)y * W_DIM;
    #pragma unroll
    for (int i = 0; i < 5; ++i) {
        const int u = i * NT + tid;                  // unit = 16 B
        if (u < 1152) {                              // tail is wave-aligned (u<1152 <=> tid<128 at i=4)
            const int k   = u >> 7;                  // wave-uniform (128 | wave base)
            const int c16 = u & 127;
            gload_lds16((const char*)(Fb + (size_t)k * PLANE) + (c16 << 4),
                        (char*)ldsF + (((i * NT) + (tid & ~63)) << 4));
        }
    }

    // ---- stage Qg halo rows (L2/L3-warm): 3 x 512 uint4 = 1536 units
    const int ym[3] = { max(y - 1, 0), y, min(y + 1, H_DIM - 1) };
    const uint4* __restrict__ Qb = Qg + (size_t)b * PLANE;
    #pragma unroll
    for (int i = 0; i < 6; ++i) {
        const int u   = i * NT + tid;
        const int r   = u >> 9;                      // wave-uniform (512 | wave base)
        const int col = u & 511;
        gload_lds16(Qb + (size_t)ym[r] * W_DIM + col,
                    (char*)ldsQ + (((i * NT) + (tid & ~63)) << 4));
    }

    // ---- logit direct loads (L3-hot, K1-proven pattern) ----
    const int x = tid * 2;
    const size_t pix = (size_t)y * W_DIM + x;
    const float* __restrict__ lp = logit + (size_t)b * C_DIM * PLANE + pix;
    float2 lg[C_DIM];
    #pragma unroll
    for (int c = 0; c < C_DIM; ++c) lg[c] = *(const float2*)(lp + (size_t)c * PLANE);

    build_E_nosync(matrix, E4, tid);
    __syncthreads();   // drains vmcnt(0): all global_load_lds landed; E4 visible

    // ---- filter: taps from ldsQ, weights from ldsF ----
    const bool vyr[3] = { y > 0, true, y < H_DIM - 1 };
    const int cols[4] = { max(x - 1, 0), x, x + 1, min(x + 2, W_DIM - 1) };
    const bool vxc[4] = { x > 0, true, true, x + 2 < W_DIM };

    float og[G_DIM][2];
    #pragma unroll
    for (int g = 0; g < G_DIM; ++g) { og[g][0] = 0.0f; og[g][1] = 0.0f; }

    #pragma unroll
    for (int r = 0; r < 3; ++r) {
        const uint4 q0 = ldsQ[r * W_DIM + cols[0]];
        const uint4 q1 = ldsQ[r * W_DIM + cols[1]];
        const uint4 q2 = ldsQ[r * W_DIM + cols[2]];
        const uint4 q3 = ldsQ[r * W_DIM + cols[3]];
        const uint4 qv_[4] = { q0, q1, q2, q3 };

        #pragma unroll
        for (int dxi = 0; dxi < 3; ++dxi) {
            const int k = r * 3 + dxi;
            const float wkv[2] = { ldsF[k * W_DIM + x], ldsF[k * W_DIM + x + 1] };
            #pragma unroll
            for (int j = 0; j < 2; ++j) {
                const bool v = vyr[r] & vxc[j + dxi];
                const float wv = v ? wkv[j] : 0.0f;
                const uint4 qv = qv_[j + dxi];
                og[0][j] = fmaf(wv, up_lo(qv.x), og[0][j]);
                og[1][j] = fmaf(wv, up_hi(qv.x), og[1][j]);
                og[2][j] = fmaf(wv, up_lo(qv.y), og[2][j]);
                og[3][j] = fmaf(wv, up_hi(qv.y), og[3][j]);
                og[4][j] = fmaf(wv, up_lo(qv.z), og[4][j]);
                og[5][j] = fmaf(wv, up_hi(qv.z), og[5][j]);
                og[6][j] = fmaf(wv, up_lo(qv.w), og[6][j]);
                og[7][j] = fmaf(wv, up_hi(qv.w), og[7][j]);
            }
        }
    }

    // ---- decode + subtract + nt-store ----
    float* __restrict__ op = out + (size_t)b * C_DIM * PLANE + pix;
    #pragma unroll
    for (int c = 0; c < C_DIM; ++c) {
        const float4 E0 = E4[c][0];
        const float4 E1 = E4[c][1];
        float d0 = og[0][0] * E0.x;
        float d1 = og[0][1] * E0.x;
        d0 = fmaf(og[1][0], E0.y, d0);  d1 = fmaf(og[1][1], E0.y, d1);
        d0 = fmaf(og[2][0], E0.z, d0);  d1 = fmaf(og[2][1], E0.z, d1);
        d0 = fmaf(og[3][0], E0.w, d0);  d1 = fmaf(og[3][1], E0.w, d1);
        d0 = fmaf(og[4][0], E1.x, d0);  d1 = fmaf(og[4][1], E1.x, d1);
        d0 = fmaf(og[5][0], E1.y, d0);  d1 = fmaf(og[5][1], E1.y, d1);
        d0 = fmaf(og[6][0], E1.z, d0);  d1 = fmaf(og[6][1], E1.z, d1);
        d0 = fmaf(og[7][0], E1.w, d0);  d1 = fmaf(og[7][1], E1.w, d1);
        ntstore2(op + (size_t)c * PLANE, lg[c].x - d0, lg[c].y - d1);
    }
}

extern "C" void kernel_launch(void* const* d_in, const int* in_sizes, int n_in,
                              void* d_out, int out_size, void* d_ws, size_t ws_size,
                              hipStream_t stream) {
    const float* F      = (const float*)d_in[0];   // [4, 9, 512, 512]
    const float* logit  = (const float*)d_in[1];   // [4, 19, 512, 512]
    const float* matrix = (const float*)d_in[2];   // [8, 19, 1, 1]
    float* out = (float*)d_out;                    // [4, 19, 512, 512]
    uint4* Qg = (uint4*)d_ws;                      // 16.8 MB: [4][512][512] x 8 bf16

    qg_encode <<<NPIX / (2 * NT), NT, 0, stream>>>(logit, matrix, Qg);
    crf_decode<<<NPIX / (2 * NT), NT, 0, stream>>>(F, logit, matrix, Qg, out);
}